// Round 8
// baseline (1052.424 us; speedup 1.0000x reference)
//
#include <hip/hip_runtime.h>
#include <hip/hip_bf16.h>

#define N_ROWS 100000
#define IN_C   128
#define OUT_C  64
#define S_SC   3
#define NNZ    1600000
#define NMAT   7

#define NCH    16            // hist chunk-copies (parallelism only)
#define HROWS  (N_ROWS / 2)  // u16-pair words per copy

#define SEG       512
#define BLKS_SCAN 196   // 196*512 = 100352 >= 100000

#define NSEG   (NNZ / 256)   // 6250 256-edge segments
#define RPB    25000         // rows per histogram bin
#define NBIN_H 4             // 4*25000 = 100000 exact

#define RPB_F  1024                          // rows per fill bucket (2^10)
#define NBKT   98                            // ceil(100000/1024)
#define EPB_A  1024                          // edges per fill_a block (LDS 13.9KB)
#define BLKS_A 1563                          // ceil(NNZ/EPB_A)
#define RS_STR (N_ROWS + 1)                  // row_start stride (CSR-style)

#define GH     2048                          // gather blocks per half launch
#define RHALF  50000

struct RowPtrs { const int* p[NMAT]; };

__device__ __forceinline__ float bf2f(__hip_bfloat16 x) { return __bfloat162float(x); }

// ---------------------------------------------------------------------------
// 1) Binned histogram, zero global atomics. 16 chunk-copies, u16 counts.
// ---------------------------------------------------------------------------
__global__ __launch_bounds__(512)
void hist_binned(RowPtrs P, unsigned* __restrict__ counts16)
{
    __shared__ unsigned cnt[RPB / 2];
    const int m    = blockIdx.y;
    const int c    = blockIdx.x & (NCH - 1);
    const int bin0 = (blockIdx.x >> 4) * RPB;
    const int t    = threadIdx.x;

    for (int i = t; i < RPB / 2; i += 512) cnt[i] = 0;
    __syncthreads();

    const int* rows = P.p[m];
    const int wv = t >> 6;
    const int ln = t & 63;

    for (int sg = c + NCH * wv; sg < NSEG; sg += NCH * 8) {
        const int4 v = ((const int4*)rows)[sg * 64 + ln];
        unsigned i0 = (unsigned)(v.x - bin0);
        unsigned i1 = (unsigned)(v.y - bin0);
        unsigned i2 = (unsigned)(v.z - bin0);
        unsigned i3 = (unsigned)(v.w - bin0);
        if (i0 < RPB) atomicAdd(&cnt[i0 >> 1], 1u << ((i0 & 1) * 16));
        if (i1 < RPB) atomicAdd(&cnt[i1 >> 1], 1u << ((i1 & 1) * 16));
        if (i2 < RPB) atomicAdd(&cnt[i2 >> 1], 1u << ((i2 & 1) * 16));
        if (i3 < RPB) atomicAdd(&cnt[i3 >> 1], 1u << ((i3 & 1) * 16));
    }
    __syncthreads();

    unsigned* dst = counts16 + ((size_t)m * NCH + c) * HROWS + (bin0 >> 1);
    for (int i = t; i < RPB / 2; i += 512) dst[i] = cnt[i];
}

// ---------------------------------------------------------------------------
// 2a) Per-512-row block scan of totals (sum over 16 u16 copies) + block sums
// ---------------------------------------------------------------------------
__global__ __launch_bounds__(256)
void scan_l1(const unsigned* __restrict__ counts16, int* __restrict__ rs,
             int* __restrict__ bsum)
{
    __shared__ int buf[2][SEG];
    const int m   = blockIdx.y;
    const int blk = blockIdx.x;
    const int t   = threadIdx.x;
    const unsigned* cnt = counts16 + (size_t)m * NCH * HROWS;

    for (int k = t; k < SEG; k += 256) {
        const int g = blk * SEG + k;
        int tot = 0;
        if (g < N_ROWS) {
            const int wi = g >> 1, sh = (g & 1) * 16;
            for (int c = 0; c < NCH; ++c)
                tot += (int)((cnt[(size_t)c * HROWS + wi] >> sh) & 0xffffu);
        }
        buf[0][k] = tot;
    }
    __syncthreads();

    int src = 0;
    for (int off = 1; off < SEG; off <<= 1) {
        for (int k = t; k < SEG; k += 256) {
            int v = buf[src][k];
            if (k >= off) v += buf[src][k - off];
            buf[1 - src][k] = v;
        }
        src ^= 1;
        __syncthreads();
    }
    for (int k = t; k < SEG; k += 256) {
        const int g = blk * SEG + k;
        if (g < N_ROWS)
            rs[(size_t)m * RS_STR + g] = (k == 0) ? 0 : buf[src][k - 1];
    }
    if (t == 0) bsum[m * 256 + blk] = buf[src][SEG - 1];
}

// ---------------------------------------------------------------------------
// 2b) Exclusive scan of block sums; one block per matrix
// ---------------------------------------------------------------------------
__global__ __launch_bounds__(256)
void scan_l2(int* __restrict__ bsum)
{
    __shared__ int buf[2][256];
    const int t = threadIdx.x;
    int* b = bsum + blockIdx.x * 256;
    buf[0][t] = (t < BLKS_SCAN) ? b[t] : 0;
    __syncthreads();
    int src = 0;
    for (int off = 1; off < 256; off <<= 1) {
        int v = buf[src][t];
        if (t >= off) v += buf[src][t - off];
        buf[1 - src][t] = v;
        src ^= 1;
        __syncthreads();
    }
    if (t < BLKS_SCAN) b[t] = (t == 0) ? 0 : buf[src][t - 1];
}

// ---------------------------------------------------------------------------
// 2c) Finalize: absolute row starts; bucket cursors; terminal NNZ sentinel
// ---------------------------------------------------------------------------
__global__ __launch_bounds__(256)
void finalize(const int* __restrict__ bsum, int* __restrict__ rs,
              int* __restrict__ bucket_cur)
{
    const int i = blockIdx.x * 256 + threadIdx.x;
    if (i >= NMAT * N_ROWS) return;
    const int m = i / N_ROWS;
    const int r = i - m * N_ROWS;
    const size_t ri = (size_t)m * RS_STR + r;
    const int base = rs[ri] + bsum[m * 256 + r / SEG];
    rs[ri] = base;
    if ((r & (RPB_F - 1)) == 0) bucket_cur[m * NBKT + (r >> 10)] = base;
    if (r == 0) rs[(size_t)m * RS_STR + N_ROWS] = NNZ;
}

// ---------------------------------------------------------------------------
// fill_a body: bucket scatter (LDS reorder, 98 reservation atomics/block)
// EPB_A=1024 -> FaLds ~13.9 KB, keeps fused-gather occupancy at max.
// ---------------------------------------------------------------------------
struct FaLds {
    int cnt[NBKT], lofs[NBKT], lcur[NBKT], gbase[NBKT];
    uint2 stg[EPB_A];
    int gpos[EPB_A];
};

__device__ __forceinline__ void fill_a_body(FaLds& L, int blk,
    const int* __restrict__ rows, const int* __restrict__ cols,
    const float* __restrict__ vals, int* __restrict__ bcur,
    uint2* __restrict__ bkt)
{
    const int t  = threadIdx.x;
    const int e0 = blk * EPB_A;
    const int n  = min(EPB_A, NNZ - e0);

    for (int b = t; b < NBKT; b += 256) L.cnt[b] = 0;
    __syncthreads();

    int rr[4], cc[4], bb[4]; unsigned vv[4];
    #pragma unroll
    for (int k = 0; k < 4; ++k) {
        const int idx = t + k * 256;
        if (idx < n) {
            const int e = e0 + idx;
            rr[k] = rows[e];
            cc[k] = cols[e];
            vv[k] = __float_as_uint(vals[e]);
            bb[k] = rr[k] >> 10;
            atomicAdd(&L.cnt[bb[k]], 1);
        } else bb[k] = -1;
    }
    __syncthreads();

    if (t == 0) {
        int run = 0;
        for (int b = 0; b < NBKT; ++b) { L.lofs[b] = run; run += L.cnt[b]; }
    }
    __syncthreads();
    if (t < NBKT) {
        L.gbase[t] = atomicAdd(&bcur[t], L.cnt[t]);
        L.lcur[t]  = L.lofs[t];
    }
    __syncthreads();

    #pragma unroll
    for (int k = 0; k < 4; ++k) {
        if (bb[k] >= 0) {
            const int p = atomicAdd(&L.lcur[bb[k]], 1);
            L.stg[p]  = make_uint2(((unsigned)(rr[k] & (RPB_F - 1)) << 17) |
                                   (unsigned)cc[k], vv[k]);
            L.gpos[p] = L.gbase[bb[k]] + (p - L.lofs[bb[k]]);
        }
    }
    __syncthreads();

    for (int p = t; p < n; p += 256) bkt[L.gpos[p]] = L.stg[p];
}

// ---------------------------------------------------------------------------
// fill_b body: per-bucket fill with private LDS cursors
// ---------------------------------------------------------------------------
__device__ __forceinline__ void fill_b_body(int* cur, int b,
    const int* __restrict__ rs_m, const uint2* __restrict__ bkt,
    uint2* __restrict__ scv)
{
    const int r0 = b << 10;
    const int nr = min(RPB_F, N_ROWS - r0);
    const int t  = threadIdx.x;

    for (int i = t; i < nr; i += 256) cur[i] = rs_m[r0 + i];
    __syncthreads();

    const int e0 = rs_m[r0];
    const int e1 = rs_m[min(r0 + RPB_F, N_ROWS)];
    for (int e = e0 + t; e < e1; e += 256) {
        const uint2 rec = bkt[e];
        const int rl = (int)(rec.x >> 17);
        const int p  = atomicAdd(&cur[rl], 1);
        scv[p] = make_uint2(rec.x & 0x1FFFFu, rec.y);
    }
}

// ---------------------------------------------------------------------------
// standalone fill kernels (used for matrix 0 head)
// ---------------------------------------------------------------------------
__global__ __launch_bounds__(256)
void fill_a(const int* __restrict__ rows, const int* __restrict__ cols,
            const float* __restrict__ vals, int* __restrict__ bcur,
            uint2* __restrict__ bkt)
{
    __shared__ FaLds L;
    fill_a_body(L, blockIdx.x, rows, cols, vals, bcur, bkt);
}

__global__ __launch_bounds__(256)
void fill_b(const int* __restrict__ rs_m, const uint2* __restrict__ bkt,
            uint2* __restrict__ scv)
{
    __shared__ int cur[RPB_F];
    fill_b_body(cur, blockIdx.x, rs_m, bkt, scv);
}

// ---------------------------------------------------------------------------
// gather body, unroll 8/4/1.
// GMODE 0: src = LDS fp32 W -> bf16 dst.  GMODE 1: bf16 src * theta -> bf16.
// GMODE 2: bf16 src, relu -> fp32 out[:,sc,:].
// ---------------------------------------------------------------------------
template <int GMODE>
__device__ __forceinline__ float fetch_src(const float* Wl,
                                           const __hip_bfloat16* src,
                                           unsigned cx, int lane)
{
    if constexpr (GMODE == 0) return Wl[cx * OUT_C + lane];
    else return bf2f(src[(size_t)cx * OUT_C + lane]);
}

template <int GMODE>
__device__ __forceinline__ void gather_body(const float* Wl,
    const int* __restrict__ rs_m, const uint2* __restrict__ scv,
    const void* __restrict__ srcv, const float* __restrict__ theta,
    __hip_bfloat16* __restrict__ dstb, float* __restrict__ dstf,
    int scale, int r0, int r1, int wave, int nw, int lane)
{
    const __hip_bfloat16* src = (const __hip_bfloat16*)srcv;

    for (int r = r0 + wave; r < r1; r += nw) {
        const int s = rs_m[r], t = rs_m[r + 1];
        float a0 = 0.f, a1 = 0.f, a2 = 0.f, a3 = 0.f;
        float a4 = 0.f, a5 = 0.f, a6 = 0.f, a7 = 0.f;
        int j = s;
        for (; j + 7 < t; j += 8) {
            const uint2 p0 = scv[j],     p1 = scv[j + 1];
            const uint2 p2 = scv[j + 2], p3 = scv[j + 3];
            const uint2 p4 = scv[j + 4], p5 = scv[j + 5];
            const uint2 p6 = scv[j + 6], p7 = scv[j + 7];
            const float w0 = fetch_src<GMODE>(Wl, src, p0.x, lane);
            const float w1 = fetch_src<GMODE>(Wl, src, p1.x, lane);
            const float w2 = fetch_src<GMODE>(Wl, src, p2.x, lane);
            const float w3 = fetch_src<GMODE>(Wl, src, p3.x, lane);
            const float w4 = fetch_src<GMODE>(Wl, src, p4.x, lane);
            const float w5 = fetch_src<GMODE>(Wl, src, p5.x, lane);
            const float w6 = fetch_src<GMODE>(Wl, src, p6.x, lane);
            const float w7 = fetch_src<GMODE>(Wl, src, p7.x, lane);
            a0 += __uint_as_float(p0.y) * w0;
            a1 += __uint_as_float(p1.y) * w1;
            a2 += __uint_as_float(p2.y) * w2;
            a3 += __uint_as_float(p3.y) * w3;
            a4 += __uint_as_float(p4.y) * w4;
            a5 += __uint_as_float(p5.y) * w5;
            a6 += __uint_as_float(p6.y) * w6;
            a7 += __uint_as_float(p7.y) * w7;
        }
        for (; j + 3 < t; j += 4) {
            const uint2 p0 = scv[j],     p1 = scv[j + 1];
            const uint2 p2 = scv[j + 2], p3 = scv[j + 3];
            const float w0 = fetch_src<GMODE>(Wl, src, p0.x, lane);
            const float w1 = fetch_src<GMODE>(Wl, src, p1.x, lane);
            const float w2 = fetch_src<GMODE>(Wl, src, p2.x, lane);
            const float w3 = fetch_src<GMODE>(Wl, src, p3.x, lane);
            a0 += __uint_as_float(p0.y) * w0;
            a1 += __uint_as_float(p1.y) * w1;
            a2 += __uint_as_float(p2.y) * w2;
            a3 += __uint_as_float(p3.y) * w3;
        }
        for (; j < t; ++j) {
            const uint2 p = scv[j];
            a0 += __uint_as_float(p.y) * fetch_src<GMODE>(Wl, src, p.x, lane);
        }
        const float acc = ((a0 + a1) + (a2 + a3)) + ((a4 + a5) + (a6 + a7));
        if (GMODE == 0) {
            dstb[(size_t)r * OUT_C + lane] = __float2bfloat16(acc);
        } else if (GMODE == 1) {
            dstb[(size_t)r * OUT_C + lane] = __float2bfloat16(theta[r] * acc);
        } else {
            dstf[((size_t)r * S_SC + scale) * OUT_C + lane] = acc > 0.0f ? acc : 0.0f;
        }
    }
}

// ---------------------------------------------------------------------------
// Fused launch: blocks [0,nFill) do fill work (kind 1 = fill_a, 2 = fill_b)
// for the NEXT matrix; blocks [nFill, nFill+GH) gather rows [r0,r1) of the
// CURRENT matrix. Fill blocks first so they dispatch immediately.
// ---------------------------------------------------------------------------
template <int GMODE>
__global__ __launch_bounds__(256)
void fused_gf(int nFill, int fillKind,
              const int* faRows, const int* faCols, const float* faVals,
              int* faBcur,
              const int* fbRs, uint2* bkt, uint2* fbScv,
              const int* gRs, const uint2* gScv, const void* gSrc,
              const float* theta, __hip_bfloat16* dstb, float* dstf,
              int scale, int r0, int r1)
{
    constexpr int WLN = (GMODE == 0) ? (IN_C * OUT_C) : 1;
    __shared__ union ULds {
        FaLds fa;
        int   fbcur[RPB_F];
        float Wl[WLN];
    } u;

    const int t = threadIdx.x;
    if ((int)blockIdx.x < nFill) {
        if (fillKind == 1)
            fill_a_body(u.fa, blockIdx.x, faRows, faCols, faVals, faBcur, bkt);
        else
            fill_b_body(u.fbcur, blockIdx.x, fbRs, bkt, fbScv);
        return;
    }

    const int gb   = (int)blockIdx.x - nFill;
    const int lane = t & 63;
    const int wave = gb * 4 + (t >> 6);
    const int nw   = ((int)gridDim.x - nFill) * 4;

    const float* Wl = nullptr;
    if constexpr (GMODE == 0) {
        const float* W = (const float*)gSrc;
        for (int i = t; i < IN_C * OUT_C; i += 256) u.Wl[i] = W[i];
        __syncthreads();
        Wl = u.Wl;
    }
    gather_body<GMODE>(Wl, gRs, gScv, gSrc, theta, dstb, dstf,
                       scale, r0, r1, wave, nw, lane);
}

// ---------------------------------------------------------------------------
extern "C" void kernel_launch(void* const* d_in, const int* in_sizes, int n_in,
                              void* d_out, int out_size, void* d_ws, size_t ws_size,
                              hipStream_t stream)
{
    const int*   phi_idx  = (const int*)d_in[0];
    const float* phi_val  = (const float*)d_in[1];
    const int*   pinv_idx = (const int*)d_in[2];
    const float* pinv_val = (const float*)d_in[3];
    const int*   fidx     = (const int*)d_in[4];
    const float* fval     = (const float*)d_in[5];
    const float* W        = (const float*)d_in[6];
    const float* theta    = (const float*)d_in[7];
    float*       out      = (float*)d_out;          // (N,S,64) fp32

    // ---- workspace (≈76.4 MB; 76.8 MB proven) ----
    __hip_bfloat16* filtered = (__hip_bfloat16*)d_ws;                  // 12.8 MB
    __hip_bfloat16* z        = filtered + (size_t)N_ROWS * OUT_C;      // 12.8 MB
    uint2* bkt  = (uint2*)(z + (size_t)N_ROWS * OUT_C);                // 12.8 MB
    uint2* scv0 = bkt + NNZ;                                           // 12.8 MB
    unsigned* counts16 = (unsigned*)(scv0 + NNZ);                      // 22.4 MB
    uint2* scv1 = (uint2*)counts16;     // overlay: counts16 dead after scan_l1
    int*   rs         = (int*)(counts16 + (size_t)NMAT * NCH * HROWS); // 2.8 MB
    int*   bsum       = rs + (size_t)NMAT * RS_STR;                    // 7 KB
    int*   bucket_cur = bsum + NMAT * 256;                             // 2.7 KB

    // matrix order k: 0=F, per scale i: 1+2i=PhiInv_i, 2+2i=Phi_i
    RowPtrs P;
    const int* kRows[NMAT]; const int* kCols[NMAT]; const float* kVals[NMAT];
    kRows[0] = fidx; kCols[0] = fidx + NNZ; kVals[0] = fval;
    for (int i = 0; i < S_SC; ++i) {
        kRows[1 + 2 * i] = pinv_idx + (size_t)(2 * i) * NNZ;
        kCols[1 + 2 * i] = pinv_idx + (size_t)(2 * i + 1) * NNZ;
        kVals[1 + 2 * i] = pinv_val + (size_t)i * NNZ;
        kRows[2 + 2 * i] = phi_idx + (size_t)(2 * i) * NNZ;
        kCols[2 + 2 * i] = phi_idx + (size_t)(2 * i + 1) * NNZ;
        kVals[2 + 2 * i] = phi_val + (size_t)i * NNZ;
    }
    for (int k = 0; k < NMAT; ++k) P.p[k] = kRows[k];

    // ---- batched CSR metadata for all 7 matrices ----
    hist_binned<<<dim3(NCH * NBIN_H, NMAT), 512, 0, stream>>>(P, counts16);
    scan_l1<<<dim3(BLKS_SCAN, NMAT), 256, 0, stream>>>(counts16, rs, bsum);
    scan_l2<<<NMAT, 256, 0, stream>>>(bsum);
    finalize<<<(NMAT * N_ROWS + 255) / 256, 256, 0, stream>>>(bsum, rs, bucket_cur);

    // ---- head: fill matrix 0 ----
    fill_a<<<BLKS_A, 256, 0, stream>>>(kRows[0], kCols[0], kVals[0],
                                       bucket_cur, bkt);
    fill_b<<<NBKT, 256, 0, stream>>>(rs, bkt, scv0);

    // ---- pipelined gather(k) || fill(k+1) ----
    for (int k = 0; k < NMAT; ++k) {
        const uint2* gs   = (k & 1) ? scv1 : scv0;
        const int*   grs  = rs + (size_t)k * RS_STR;
        const void*  gsrc = (k == 0) ? (const void*)W
                          : (k & 1)  ? (const void*)filtered : (const void*)z;
        __hip_bfloat16* db = (k == 0) ? filtered : ((k & 1) ? z : nullptr);
        const bool isOut = (k >= 2) && !(k & 1);
        float* df = isOut ? out : nullptr;
        const int sc = isOut ? (k - 2) / 2 : 0;
        const int gm = (k == 0) ? 0 : ((k & 1) ? 1 : 2);

        const int  kn      = k + 1;
        const bool hasNext = kn < NMAT;
        uint2* ns = (kn & 1) ? scv1 : scv0;

        const int nFa = hasNext ? BLKS_A : 0;
        const int nFb = hasNext ? NBKT : 0;

        // half 1: gather rows [0,RHALF) || fill_a(k+1)
        switch (gm) {
        case 0: fused_gf<0><<<nFa + GH, 256, 0, stream>>>(nFa, 1,
                    hasNext ? kRows[kn] : nullptr, hasNext ? kCols[kn] : nullptr,
                    hasNext ? kVals[kn] : nullptr,
                    hasNext ? bucket_cur + kn * NBKT : nullptr,
                    nullptr, bkt, nullptr,
                    grs, gs, gsrc, theta, db, df, sc, 0, RHALF); break;
        case 1: fused_gf<1><<<nFa + GH, 256, 0, stream>>>(nFa, 1,
                    hasNext ? kRows[kn] : nullptr, hasNext ? kCols[kn] : nullptr,
                    hasNext ? kVals[kn] : nullptr,
                    hasNext ? bucket_cur + kn * NBKT : nullptr,
                    nullptr, bkt, nullptr,
                    grs, gs, gsrc, theta, db, df, sc, 0, RHALF); break;
        default: fused_gf<2><<<nFa + GH, 256, 0, stream>>>(nFa, 1,
                    hasNext ? kRows[kn] : nullptr, hasNext ? kCols[kn] : nullptr,
                    hasNext ? kVals[kn] : nullptr,
                    hasNext ? bucket_cur + kn * NBKT : nullptr,
                    nullptr, bkt, nullptr,
                    grs, gs, gsrc, theta, db, df, sc, 0, RHALF); break;
        }
        // half 2: gather rows [RHALF,N) || fill_b(k+1)
        switch (gm) {
        case 0: fused_gf<0><<<nFb + GH, 256, 0, stream>>>(nFb, 2,
                    nullptr, nullptr, nullptr, nullptr,
                    hasNext ? rs + (size_t)kn * RS_STR : nullptr, bkt,
                    hasNext ? ns : nullptr,
                    grs, gs, gsrc, theta, db, df, sc, RHALF, N_ROWS); break;
        case 1: fused_gf<1><<<nFb + GH, 256, 0, stream>>>(nFb, 2,
                    nullptr, nullptr, nullptr, nullptr,
                    hasNext ? rs + (size_t)kn * RS_STR : nullptr, bkt,
                    hasNext ? ns : nullptr,
                    grs, gs, gsrc, theta, db, df, sc, RHALF, N_ROWS); break;
        default: fused_gf<2><<<nFb + GH, 256, 0, stream>>>(nFb, 2,
                    nullptr, nullptr, nullptr, nullptr,
                    hasNext ? rs + (size_t)kn * RS_STR : nullptr, bkt,
                    hasNext ? ns : nullptr,
                    grs, gs, gsrc, theta, db, df, sc, RHALF, N_ROWS); break;
        }
    }
}

// Round 9
// 999.445 us; speedup vs baseline: 1.0530x; 1.0530x over previous
//
#include <hip/hip_runtime.h>
#include <hip/hip_bf16.h>

#define N_ROWS 100000
#define IN_C   128
#define OUT_C  64
#define S_SC   3
#define NNZ    1600000
#define NMAT   7

#define NCH    16            // hist chunk-copies (parallelism only)
#define HROWS  (N_ROWS / 2)  // u16-pair words per copy

#define SEG       512
#define BLKS_SCAN 196   // 196*512 = 100352 >= 100000

#define NSEG   (NNZ / 256)   // 6250 256-edge segments
#define RPB    25000         // rows per histogram bin
#define NBIN_H 4             // 4*25000 = 100000 exact

#define RPB_F  1024                          // rows per fill bucket (2^10)
#define NBKT   98                            // ceil(100000/1024)
#define EPB_A  2048                          // edges per fill_a block (r7 best)
#define BLKS_A 782                           // ceil(NNZ/EPB_A)
#define RS_STR (N_ROWS + 1)                  // row_start stride (CSR-style)

#define GH     2048                          // gather blocks per half launch
#define RHALF  50000

struct RowPtrs { const int* p[NMAT]; };

__device__ __forceinline__ float bf2f(__hip_bfloat16 x) { return __bfloat162float(x); }

// ---------------------------------------------------------------------------
// 1) Binned histogram, zero global atomics. 16 chunk-copies, u16 counts.
// ---------------------------------------------------------------------------
__global__ __launch_bounds__(512)
void hist_binned(RowPtrs P, unsigned* __restrict__ counts16)
{
    __shared__ unsigned cnt[RPB / 2];
    const int m    = blockIdx.y;
    const int c    = blockIdx.x & (NCH - 1);
    const int bin0 = (blockIdx.x >> 4) * RPB;
    const int t    = threadIdx.x;

    for (int i = t; i < RPB / 2; i += 512) cnt[i] = 0;
    __syncthreads();

    const int* rows = P.p[m];
    const int wv = t >> 6;
    const int ln = t & 63;

    for (int sg = c + NCH * wv; sg < NSEG; sg += NCH * 8) {
        const int4 v = ((const int4*)rows)[sg * 64 + ln];
        unsigned i0 = (unsigned)(v.x - bin0);
        unsigned i1 = (unsigned)(v.y - bin0);
        unsigned i2 = (unsigned)(v.z - bin0);
        unsigned i3 = (unsigned)(v.w - bin0);
        if (i0 < RPB) atomicAdd(&cnt[i0 >> 1], 1u << ((i0 & 1) * 16));
        if (i1 < RPB) atomicAdd(&cnt[i1 >> 1], 1u << ((i1 & 1) * 16));
        if (i2 < RPB) atomicAdd(&cnt[i2 >> 1], 1u << ((i2 & 1) * 16));
        if (i3 < RPB) atomicAdd(&cnt[i3 >> 1], 1u << ((i3 & 1) * 16));
    }
    __syncthreads();

    unsigned* dst = counts16 + ((size_t)m * NCH + c) * HROWS + (bin0 >> 1);
    for (int i = t; i < RPB / 2; i += 512) dst[i] = cnt[i];
}

// ---------------------------------------------------------------------------
// 2a) Per-512-row block scan of totals (sum over 16 u16 copies) + block sums
// ---------------------------------------------------------------------------
__global__ __launch_bounds__(256)
void scan_l1(const unsigned* __restrict__ counts16, int* __restrict__ rs,
             int* __restrict__ bsum)
{
    __shared__ int buf[2][SEG];
    const int m   = blockIdx.y;
    const int blk = blockIdx.x;
    const int t   = threadIdx.x;
    const unsigned* cnt = counts16 + (size_t)m * NCH * HROWS;

    for (int k = t; k < SEG; k += 256) {
        const int g = blk * SEG + k;
        int tot = 0;
        if (g < N_ROWS) {
            const int wi = g >> 1, sh = (g & 1) * 16;
            for (int c = 0; c < NCH; ++c)
                tot += (int)((cnt[(size_t)c * HROWS + wi] >> sh) & 0xffffu);
        }
        buf[0][k] = tot;
    }
    __syncthreads();

    int src = 0;
    for (int off = 1; off < SEG; off <<= 1) {
        for (int k = t; k < SEG; k += 256) {
            int v = buf[src][k];
            if (k >= off) v += buf[src][k - off];
            buf[1 - src][k] = v;
        }
        src ^= 1;
        __syncthreads();
    }
    for (int k = t; k < SEG; k += 256) {
        const int g = blk * SEG + k;
        if (g < N_ROWS)
            rs[(size_t)m * RS_STR + g] = (k == 0) ? 0 : buf[src][k - 1];
    }
    if (t == 0) bsum[m * 256 + blk] = buf[src][SEG - 1];
}

// ---------------------------------------------------------------------------
// 2b) Exclusive scan of block sums; one block per matrix
// ---------------------------------------------------------------------------
__global__ __launch_bounds__(256)
void scan_l2(int* __restrict__ bsum)
{
    __shared__ int buf[2][256];
    const int t = threadIdx.x;
    int* b = bsum + blockIdx.x * 256;
    buf[0][t] = (t < BLKS_SCAN) ? b[t] : 0;
    __syncthreads();
    int src = 0;
    for (int off = 1; off < 256; off <<= 1) {
        int v = buf[src][t];
        if (t >= off) v += buf[src][t - off];
        buf[1 - src][t] = v;
        src ^= 1;
        __syncthreads();
    }
    if (t < BLKS_SCAN) b[t] = (t == 0) ? 0 : buf[src][t - 1];
}

// ---------------------------------------------------------------------------
// 2c) Finalize: absolute row starts; bucket cursors; terminal NNZ sentinel
// ---------------------------------------------------------------------------
__global__ __launch_bounds__(256)
void finalize(const int* __restrict__ bsum, int* __restrict__ rs,
              int* __restrict__ bucket_cur)
{
    const int i = blockIdx.x * 256 + threadIdx.x;
    if (i >= NMAT * N_ROWS) return;
    const int m = i / N_ROWS;
    const int r = i - m * N_ROWS;
    const size_t ri = (size_t)m * RS_STR + r;
    const int base = rs[ri] + bsum[m * 256 + r / SEG];
    rs[ri] = base;
    if ((r & (RPB_F - 1)) == 0) bucket_cur[m * NBKT + (r >> 10)] = base;
    if (r == 0) rs[(size_t)m * RS_STR + N_ROWS] = NNZ;
}

// ---------------------------------------------------------------------------
// fill_a body: bucket scatter (LDS reorder, 98 reservation atomics/block)
// ---------------------------------------------------------------------------
struct FaLds {
    int cnt[NBKT], lofs[NBKT], lcur[NBKT], gbase[NBKT];
    uint2 stg[EPB_A];
    int gpos[EPB_A];
};

__device__ __forceinline__ void fill_a_body(FaLds& L, int blk,
    const int* __restrict__ rows, const int* __restrict__ cols,
    const float* __restrict__ vals, int* __restrict__ bcur,
    uint2* __restrict__ bkt)
{
    const int t  = threadIdx.x;
    const int e0 = blk * EPB_A;
    const int n  = min(EPB_A, NNZ - e0);

    for (int b = t; b < NBKT; b += 256) L.cnt[b] = 0;
    __syncthreads();

    int rr[8], cc[8], bb[8]; unsigned vv[8];
    #pragma unroll
    for (int k = 0; k < 8; ++k) {
        const int idx = t + k * 256;
        if (idx < n) {
            const int e = e0 + idx;
            rr[k] = rows[e];
            cc[k] = cols[e];
            vv[k] = __float_as_uint(vals[e]);
            bb[k] = rr[k] >> 10;
            atomicAdd(&L.cnt[bb[k]], 1);
        } else bb[k] = -1;
    }
    __syncthreads();

    if (t == 0) {
        int run = 0;
        for (int b = 0; b < NBKT; ++b) { L.lofs[b] = run; run += L.cnt[b]; }
    }
    __syncthreads();
    if (t < NBKT) {
        L.gbase[t] = atomicAdd(&bcur[t], L.cnt[t]);
        L.lcur[t]  = L.lofs[t];
    }
    __syncthreads();

    #pragma unroll
    for (int k = 0; k < 8; ++k) {
        if (bb[k] >= 0) {
            const int p = atomicAdd(&L.lcur[bb[k]], 1);
            L.stg[p]  = make_uint2(((unsigned)(rr[k] & (RPB_F - 1)) << 17) |
                                   (unsigned)cc[k], vv[k]);
            L.gpos[p] = L.gbase[bb[k]] + (p - L.lofs[bb[k]]);
        }
    }
    __syncthreads();

    for (int p = t; p < n; p += 256) bkt[L.gpos[p]] = L.stg[p];
}

// ---------------------------------------------------------------------------
// fill_b body: per-bucket fill with private LDS cursors
// ---------------------------------------------------------------------------
__device__ __forceinline__ void fill_b_body(int* cur, int b,
    const int* __restrict__ rs_m, const uint2* __restrict__ bkt,
    uint2* __restrict__ scv)
{
    const int r0 = b << 10;
    const int nr = min(RPB_F, N_ROWS - r0);
    const int t  = threadIdx.x;

    for (int i = t; i < nr; i += 256) cur[i] = rs_m[r0 + i];
    __syncthreads();

    const int e0 = rs_m[r0];
    const int e1 = rs_m[min(r0 + RPB_F, N_ROWS)];
    for (int e = e0 + t; e < e1; e += 256) {
        const uint2 rec = bkt[e];
        const int rl = (int)(rec.x >> 17);
        const int p  = atomicAdd(&cur[rl], 1);
        scv[p] = make_uint2(rec.x & 0x1FFFFu, rec.y);
    }
}

// ---------------------------------------------------------------------------
// standalone fill kernels (used for matrix 0 head)
// ---------------------------------------------------------------------------
__global__ __launch_bounds__(256)
void fill_a(const int* __restrict__ rows, const int* __restrict__ cols,
            const float* __restrict__ vals, int* __restrict__ bcur,
            uint2* __restrict__ bkt)
{
    __shared__ FaLds L;
    fill_a_body(L, blockIdx.x, rows, cols, vals, bcur, bkt);
}

__global__ __launch_bounds__(256)
void fill_b(const int* __restrict__ rs_m, const uint2* __restrict__ bkt,
            uint2* __restrict__ scv)
{
    __shared__ int cur[RPB_F];
    fill_b_body(cur, blockIdx.x, rs_m, bkt, scv);
}

// ---------------------------------------------------------------------------
// gather body: ROW-PAIR merged stream. Rows (rr, rr+1) have contiguous scv
// segments [s,m) and [m,e); one 8-deep unrolled loop over [s,e) with
// wave-uniform routing (j<m) to A/B accumulators. One tail + one rs-triple
// per TWO rows; next pair's rs prefetched before the record loop.
// GMODE 0: src = LDS fp32 W. GMODE 1: bf16 src * theta. GMODE 2: relu->fp32.
// ---------------------------------------------------------------------------
template <int GMODE>
__device__ __forceinline__ float fetch_src(const float* Wl,
                                           const __hip_bfloat16* src,
                                           unsigned cx, int lane)
{
    if constexpr (GMODE == 0) return Wl[cx * OUT_C + lane];
    else return bf2f(src[(size_t)cx * OUT_C + lane]);
}

template <int GMODE>
__device__ __forceinline__ void gather_body(const float* Wl,
    const int* __restrict__ rs_m, const uint2* __restrict__ scv,
    const void* __restrict__ srcv, const float* __restrict__ theta,
    __hip_bfloat16* __restrict__ dstb, float* __restrict__ dstf,
    int scale, int r0, int r1, int wave, int nw, int lane)
{
    const __hip_bfloat16* src = (const __hip_bfloat16*)srcv;

    int rr = r0 + 2 * wave;
    if (rr >= r1) return;
    int s = rs_m[rr], m = rs_m[rr + 1], e = rs_m[rr + 2];

    while (true) {
        const int rrN = rr + 2 * nw;
        int sN = 0, mN = 0, eN = 0;
        if (rrN < r1) {                      // prefetch next pair's bounds
            sN = rs_m[rrN]; mN = rs_m[rrN + 1]; eN = rs_m[rrN + 2];
        }

        float aA0 = 0.f, aA1 = 0.f, aA2 = 0.f, aA3 = 0.f;
        float aB0 = 0.f, aB1 = 0.f, aB2 = 0.f, aB3 = 0.f;
        int j = s;
        for (; j + 7 < e; j += 8) {
            const uint2 p0 = scv[j],     p1 = scv[j + 1];
            const uint2 p2 = scv[j + 2], p3 = scv[j + 3];
            const uint2 p4 = scv[j + 4], p5 = scv[j + 5];
            const uint2 p6 = scv[j + 6], p7 = scv[j + 7];
            const float w0 = fetch_src<GMODE>(Wl, src, p0.x, lane);
            const float w1 = fetch_src<GMODE>(Wl, src, p1.x, lane);
            const float w2 = fetch_src<GMODE>(Wl, src, p2.x, lane);
            const float w3 = fetch_src<GMODE>(Wl, src, p3.x, lane);
            const float w4 = fetch_src<GMODE>(Wl, src, p4.x, lane);
            const float w5 = fetch_src<GMODE>(Wl, src, p5.x, lane);
            const float w6 = fetch_src<GMODE>(Wl, src, p6.x, lane);
            const float w7 = fetch_src<GMODE>(Wl, src, p7.x, lane);
            const float v0 = __uint_as_float(p0.y) * w0;
            const float v1 = __uint_as_float(p1.y) * w1;
            const float v2 = __uint_as_float(p2.y) * w2;
            const float v3 = __uint_as_float(p3.y) * w3;
            const float v4 = __uint_as_float(p4.y) * w4;
            const float v5 = __uint_as_float(p5.y) * w5;
            const float v6 = __uint_as_float(p6.y) * w6;
            const float v7 = __uint_as_float(p7.y) * w7;
            // wave-uniform routing: record j+k belongs to row rr iff j+k < m
            aA0 += (j + 0 < m) ? v0 : 0.f;  aB0 += (j + 0 < m) ? 0.f : v0;
            aA1 += (j + 1 < m) ? v1 : 0.f;  aB1 += (j + 1 < m) ? 0.f : v1;
            aA2 += (j + 2 < m) ? v2 : 0.f;  aB2 += (j + 2 < m) ? 0.f : v2;
            aA3 += (j + 3 < m) ? v3 : 0.f;  aB3 += (j + 3 < m) ? 0.f : v3;
            aA0 += (j + 4 < m) ? v4 : 0.f;  aB0 += (j + 4 < m) ? 0.f : v4;
            aA1 += (j + 5 < m) ? v5 : 0.f;  aB1 += (j + 5 < m) ? 0.f : v5;
            aA2 += (j + 6 < m) ? v6 : 0.f;  aB2 += (j + 6 < m) ? 0.f : v6;
            aA3 += (j + 7 < m) ? v7 : 0.f;  aB3 += (j + 7 < m) ? 0.f : v7;
        }
        for (; j < e; ++j) {
            const uint2 p = scv[j];
            const float v = __uint_as_float(p.y) *
                            fetch_src<GMODE>(Wl, src, p.x, lane);
            aA0 += (j < m) ? v : 0.f;
            aB0 += (j < m) ? 0.f : v;
        }
        const float accA = (aA0 + aA1) + (aA2 + aA3);
        const float accB = (aB0 + aB1) + (aB2 + aB3);

        if (GMODE == 0) {
            dstb[(size_t)rr * OUT_C + lane]       = __float2bfloat16(accA);
            dstb[(size_t)(rr + 1) * OUT_C + lane] = __float2bfloat16(accB);
        } else if (GMODE == 1) {
            dstb[(size_t)rr * OUT_C + lane]       = __float2bfloat16(theta[rr] * accA);
            dstb[(size_t)(rr + 1) * OUT_C + lane] = __float2bfloat16(theta[rr + 1] * accB);
        } else {
            dstf[((size_t)rr * S_SC + scale) * OUT_C + lane]       = accA > 0.f ? accA : 0.f;
            dstf[((size_t)(rr + 1) * S_SC + scale) * OUT_C + lane] = accB > 0.f ? accB : 0.f;
        }

        if (rrN >= r1) break;
        rr = rrN; s = sN; m = mN; e = eN;
    }
}

// ---------------------------------------------------------------------------
// Fused launch: blocks [0,nFill) do fill work (kind 1 = fill_a, 2 = fill_b)
// for the NEXT matrix; blocks [nFill, nFill+GH) gather rows [r0,r1) of the
// CURRENT matrix. Fill blocks first so they dispatch immediately.
// ---------------------------------------------------------------------------
template <int GMODE>
__global__ __launch_bounds__(256)
void fused_gf(int nFill, int fillKind,
              const int* faRows, const int* faCols, const float* faVals,
              int* faBcur,
              const int* fbRs, uint2* bkt, uint2* fbScv,
              const int* gRs, const uint2* gScv, const void* gSrc,
              const float* theta, __hip_bfloat16* dstb, float* dstf,
              int scale, int r0, int r1)
{
    constexpr int WLN = (GMODE == 0) ? (IN_C * OUT_C) : 1;
    __shared__ union ULds {
        FaLds fa;
        int   fbcur[RPB_F];
        float Wl[WLN];
    } u;

    const int t = threadIdx.x;
    if ((int)blockIdx.x < nFill) {
        if (fillKind == 1)
            fill_a_body(u.fa, blockIdx.x, faRows, faCols, faVals, faBcur, bkt);
        else
            fill_b_body(u.fbcur, blockIdx.x, fbRs, bkt, fbScv);
        return;
    }

    const int gb   = (int)blockIdx.x - nFill;
    const int lane = t & 63;
    const int wave = gb * 4 + (t >> 6);
    const int nw   = ((int)gridDim.x - nFill) * 4;

    const float* Wl = nullptr;
    if constexpr (GMODE == 0) {
        const float* W = (const float*)gSrc;
        for (int i = t; i < IN_C * OUT_C; i += 256) u.Wl[i] = W[i];
        __syncthreads();
        Wl = u.Wl;
    }
    gather_body<GMODE>(Wl, gRs, gScv, gSrc, theta, dstb, dstf,
                       scale, r0, r1, wave, nw, lane);
}

// ---------------------------------------------------------------------------
extern "C" void kernel_launch(void* const* d_in, const int* in_sizes, int n_in,
                              void* d_out, int out_size, void* d_ws, size_t ws_size,
                              hipStream_t stream)
{
    const int*   phi_idx  = (const int*)d_in[0];
    const float* phi_val  = (const float*)d_in[1];
    const int*   pinv_idx = (const int*)d_in[2];
    const float* pinv_val = (const float*)d_in[3];
    const int*   fidx     = (const int*)d_in[4];
    const float* fval     = (const float*)d_in[5];
    const float* W        = (const float*)d_in[6];
    const float* theta    = (const float*)d_in[7];
    float*       out      = (float*)d_out;          // (N,S,64) fp32

    // ---- workspace (≈76.4 MB; 76.8 MB proven) ----
    __hip_bfloat16* filtered = (__hip_bfloat16*)d_ws;                  // 12.8 MB
    __hip_bfloat16* z        = filtered + (size_t)N_ROWS * OUT_C;      // 12.8 MB
    uint2* bkt  = (uint2*)(z + (size_t)N_ROWS * OUT_C);                // 12.8 MB
    uint2* scv0 = bkt + NNZ;                                           // 12.8 MB
    unsigned* counts16 = (unsigned*)(scv0 + NNZ);                      // 22.4 MB
    uint2* scv1 = (uint2*)counts16;     // overlay: counts16 dead after scan_l1
    int*   rs         = (int*)(counts16 + (size_t)NMAT * NCH * HROWS); // 2.8 MB
    int*   bsum       = rs + (size_t)NMAT * RS_STR;                    // 7 KB
    int*   bucket_cur = bsum + NMAT * 256;                             // 2.7 KB

    // matrix order k: 0=F, per scale i: 1+2i=PhiInv_i, 2+2i=Phi_i
    RowPtrs P;
    const int* kRows[NMAT]; const int* kCols[NMAT]; const float* kVals[NMAT];
    kRows[0] = fidx; kCols[0] = fidx + NNZ; kVals[0] = fval;
    for (int i = 0; i < S_SC; ++i) {
        kRows[1 + 2 * i] = pinv_idx + (size_t)(2 * i) * NNZ;
        kCols[1 + 2 * i] = pinv_idx + (size_t)(2 * i + 1) * NNZ;
        kVals[1 + 2 * i] = pinv_val + (size_t)i * NNZ;
        kRows[2 + 2 * i] = phi_idx + (size_t)(2 * i) * NNZ;
        kCols[2 + 2 * i] = phi_idx + (size_t)(2 * i + 1) * NNZ;
        kVals[2 + 2 * i] = phi_val + (size_t)i * NNZ;
    }
    for (int k = 0; k < NMAT; ++k) P.p[k] = kRows[k];

    // ---- batched CSR metadata for all 7 matrices ----
    hist_binned<<<dim3(NCH * NBIN_H, NMAT), 512, 0, stream>>>(P, counts16);
    scan_l1<<<dim3(BLKS_SCAN, NMAT), 256, 0, stream>>>(counts16, rs, bsum);
    scan_l2<<<NMAT, 256, 0, stream>>>(bsum);
    finalize<<<(NMAT * N_ROWS + 255) / 256, 256, 0, stream>>>(bsum, rs, bucket_cur);

    // ---- head: fill matrix 0 ----
    fill_a<<<BLKS_A, 256, 0, stream>>>(kRows[0], kCols[0], kVals[0],
                                       bucket_cur, bkt);
    fill_b<<<NBKT, 256, 0, stream>>>(rs, bkt, scv0);

    // ---- pipelined gather(k) || fill(k+1) ----
    for (int k = 0; k < NMAT; ++k) {
        const uint2* gs   = (k & 1) ? scv1 : scv0;
        const int*   grs  = rs + (size_t)k * RS_STR;
        const void*  gsrc = (k == 0) ? (const void*)W
                          : (k & 1)  ? (const void*)filtered : (const void*)z;
        __hip_bfloat16* db = (k == 0) ? filtered : ((k & 1) ? z : nullptr);
        const bool isOut = (k >= 2) && !(k & 1);
        float* df = isOut ? out : nullptr;
        const int sc = isOut ? (k - 2) / 2 : 0;
        const int gm = (k == 0) ? 0 : ((k & 1) ? 1 : 2);

        const int  kn      = k + 1;
        const bool hasNext = kn < NMAT;
        uint2* ns = (kn & 1) ? scv1 : scv0;

        const int nFa = hasNext ? BLKS_A : 0;
        const int nFb = hasNext ? NBKT : 0;

        // half 1: gather rows [0,RHALF) || fill_a(k+1)
        switch (gm) {
        case 0: fused_gf<0><<<nFa + GH, 256, 0, stream>>>(nFa, 1,
                    hasNext ? kRows[kn] : nullptr, hasNext ? kCols[kn] : nullptr,
                    hasNext ? kVals[kn] : nullptr,
                    hasNext ? bucket_cur + kn * NBKT : nullptr,
                    nullptr, bkt, nullptr,
                    grs, gs, gsrc, theta, db, df, sc, 0, RHALF); break;
        case 1: fused_gf<1><<<nFa + GH, 256, 0, stream>>>(nFa, 1,
                    hasNext ? kRows[kn] : nullptr, hasNext ? kCols[kn] : nullptr,
                    hasNext ? kVals[kn] : nullptr,
                    hasNext ? bucket_cur + kn * NBKT : nullptr,
                    nullptr, bkt, nullptr,
                    grs, gs, gsrc, theta, db, df, sc, 0, RHALF); break;
        default: fused_gf<2><<<nFa + GH, 256, 0, stream>>>(nFa, 1,
                    hasNext ? kRows[kn] : nullptr, hasNext ? kCols[kn] : nullptr,
                    hasNext ? kVals[kn] : nullptr,
                    hasNext ? bucket_cur + kn * NBKT : nullptr,
                    nullptr, bkt, nullptr,
                    grs, gs, gsrc, theta, db, df, sc, 0, RHALF); break;
        }
        // half 2: gather rows [RHALF,N) || fill_b(k+1)
        switch (gm) {
        case 0: fused_gf<0><<<nFb + GH, 256, 0, stream>>>(nFb, 2,
                    nullptr, nullptr, nullptr, nullptr,
                    hasNext ? rs + (size_t)kn * RS_STR : nullptr, bkt,
                    hasNext ? ns : nullptr,
                    grs, gs, gsrc, theta, db, df, sc, RHALF, N_ROWS); break;
        case 1: fused_gf<1><<<nFb + GH, 256, 0, stream>>>(nFb, 2,
                    nullptr, nullptr, nullptr, nullptr,
                    hasNext ? rs + (size_t)kn * RS_STR : nullptr, bkt,
                    hasNext ? ns : nullptr,
                    grs, gs, gsrc, theta, db, df, sc, RHALF, N_ROWS); break;
        default: fused_gf<2><<<nFb + GH, 256, 0, stream>>>(nFb, 2,
                    nullptr, nullptr, nullptr, nullptr,
                    hasNext ? rs + (size_t)kn * RS_STR : nullptr, bkt,
                    hasNext ? ns : nullptr,
                    grs, gs, gsrc, theta, db, df, sc, RHALF, N_ROWS); break;
        }
    }
}